// Round 9
// baseline (202.797 us; speedup 1.0000x reference)
//
#include <hip/hip_runtime.h>
#include <cstdint>
#include <cstddef>

#define NEG 0.2f
#define CAP 10752          // padded per-bucket capacity (mean 8192, +28 sigma)
#define FINE_CAP CAP

typedef __attribute__((ext_vector_type(8))) short short8;   // 8 bf16 (4 VGPR)
typedef __attribute__((ext_vector_type(4))) float f32x4;    // MFMA acc

// ---------------------------------------------------------------------------
// bf16 helpers (RNE)
// ---------------------------------------------------------------------------
__device__ __forceinline__ unsigned short f2bf(float f) {
  unsigned u = __float_as_uint(f);
  unsigned r = (u + 0x7fffu + ((u >> 16) & 1u)) >> 16;
  return (unsigned short)r;
}

// ---------------------------------------------------------------------------
// Edge dtype sniff + cursor init + W transpose to bf16 Wt[col][k].
// R8: 8 blocks. Block 0 additionally does flag + cursor init.
// ---------------------------------------------------------------------------
__global__ __launch_bounds__(512) void k_detect(const int* __restrict__ ei32,
                                                int* __restrict__ flag,
                                                int* __restrict__ cursor,
                                                const float* __restrict__ W,
                                                unsigned short* __restrict__ Wt) {
  int t = threadIdx.x;                 // 512 threads
  int b = blockIdx.x;                  // 8 blocks
  if (b == 0) {
    cursor[t] = t * CAP;
    if (t < 64) {
      int v = ei32[2 * t + 1];
      unsigned long long bl = __ballot(v != 0);
      if (t == 0) flag[0] = (bl == 0ULL) ? 1 : 0;   // 1 = int64, 0 = int32
    }
  }
  // transpose 128x128 W (f32, row-major [k][c]) -> Wt bf16 [c][k]
  int idx = b * 512 + t;               // float4 index, 4096 total
  float4 v = ((const float4*)W)[idx];
  int k = idx >> 5;                    // 32 float4 per row
  int c = (idx & 31) * 4;
  Wt[(c + 0) * 128 + k] = f2bf(v.x);
  Wt[(c + 1) * 128 + k] = f2bf(v.y);
  Wt[(c + 2) * 128 + k] = f2bf(v.z);
  Wt[(c + 3) * 128 + k] = f2bf(v.w);
}

__device__ __forceinline__ int edge_val(const void* ei, long long idx, int is64) {
  return is64 ? (int)((const long long*)ei)[idx] : ((const int*)ei)[idx];
}

// ---------------------------------------------------------------------------
// FUSED gemm (MFMA, no LDS) + msplit (4KB LDS) kernel, 256 threads both roles.
// Ms blocks at gid%3==0; coverage grid = max(ngemm+nms, 3*nms-2); gemm_id
// bijective and sequential. [R7 lesson: no large __shared__ here — GEMM-role
// blocks allocate it too and lose occupancy.]
// ---------------------------------------------------------------------------
#define MS_CHUNK 4096
__global__ __launch_bounds__(256) void k_fused(
    const float* __restrict__ x, const unsigned short* __restrict__ Wt,
    const float* __restrict__ as_, const float* __restrict__ ad_,
    unsigned short* __restrict__ hb, float* __restrict__ a_s,
    float* __restrict__ a_d, int N,
    const void* __restrict__ ei, const int* __restrict__ flag,
    int* __restrict__ cursor, uint32_t* __restrict__ buck, int E, int nms) {
  __shared__ int hist[512];
  __shared__ int resv[512];
  int gid = blockIdx.x;
  int t = threadIdx.x;
  bool is_ms = ((gid % 3) == 0) && ((gid / 3) < nms);

  if (is_ms) {
    // ---------------- msplit ----------------
    int bid = gid / 3;
    const int is64 = flag[0];
    for (int i = t; i < 512; i += 256) hist[i] = 0;
    __syncthreads();
    long long base = (long long)bid * MS_CHUNK;
    uint32_t rec[16];
    int bb[16], rk[16];
#pragma unroll
    for (int i = 0; i < 16; ++i) {
      long long idx = base + i * 256 + t;
      bb[i] = -1;
      if (idx < E) {
        int s = edge_val(ei, idx, is64);
        int d = edge_val(ei, (long long)E + idx, is64);
        bb[i] = d >> 8;
        rec[i] = ((uint32_t)(d & 255) << 17) | (uint32_t)s;
        rk[i] = atomicAdd(&hist[bb[i]], 1);
      }
    }
    __syncthreads();
    for (int b = t; b < 512; b += 256) {
      int c = hist[b];
      resv[b] = c ? atomicAdd(&cursor[b], c) : 0;
    }
    __syncthreads();
#pragma unroll
    for (int i = 0; i < 16; ++i) {
      if (bb[i] >= 0) buck[(size_t)resv[bb[i]] + rk[i]] = rec[i];
    }
    return;
  }

  // ---------------- gemm (MFMA) ----------------
  int gemm_id = gid - min(gid / 3 + 1, nms);
  int lane = t & 63;
  int wv = t >> 6;                         // 4 waves
  int row0 = gemm_id * 64 + wv * 16;
  int r = lane & 15, o = lane >> 4;

  int arow = row0 + r;
  if (arow >= N) arow = N - 1;
  const float* xr = x + (size_t)arow * 128 + o * 8;
  short8 a[4];
#pragma unroll
  for (int kt = 0; kt < 4; ++kt) {
    float4 lo = *(const float4*)(xr + kt * 32);
    float4 hi = *(const float4*)(xr + kt * 32 + 4);
    short8 av;
    av[0] = (short)f2bf(lo.x); av[1] = (short)f2bf(lo.y);
    av[2] = (short)f2bf(lo.z); av[3] = (short)f2bf(lo.w);
    av[4] = (short)f2bf(hi.x); av[5] = (short)f2bf(hi.y);
    av[6] = (short)f2bf(hi.z); av[7] = (short)f2bf(hi.w);
    a[kt] = av;
  }

  float ats[8], atd[8];
#pragma unroll
  for (int ct = 0; ct < 8; ++ct) {
    ats[ct] = as_[ct * 16 + r];
    atd[ct] = ad_[ct * 16 + r];
  }

  f32x4 acc[8];
#pragma unroll
  for (int ct = 0; ct < 8; ++ct) acc[ct] = (f32x4){0.f, 0.f, 0.f, 0.f};
#pragma unroll
  for (int ct = 0; ct < 8; ++ct) {
    const unsigned short* wb = Wt + ((size_t)(ct * 16 + r)) * 128 + o * 8;
#pragma unroll
    for (int kt = 0; kt < 4; ++kt) {
      short8 b = *(const short8*)(wb + kt * 32);
      acc[ct] = __builtin_amdgcn_mfma_f32_16x16x32_bf16(a[kt], b, acc[ct], 0, 0, 0);
    }
  }

#pragma unroll
  for (int j = 0; j < 4; ++j) {
    int row = row0 + o * 4 + j;
    bool ok = row < N;
    float ps = 0.f, pd = 0.f;
#pragma unroll
    for (int ct = 0; ct < 8; ++ct) {
      float v = acc[ct][j];
      if (ok) hb[(size_t)row * 128 + ct * 16 + r] = f2bf(v);
      ps += v * ats[ct];
      pd += v * atd[ct];
    }
#pragma unroll
    for (int d = 1; d <= 8; d <<= 1) {
      ps += __shfl_xor(ps, d);
      pd += __shfl_xor(pd, d);
    }
    if (ok && r == 0) { a_s[row] = ps; a_d[row] = pd; }
  }
}

// ---------------------------------------------------------------------------
// FALLBACK PATH (proven R8): k_fine + k_agg, buck lives in d_out.
// ---------------------------------------------------------------------------
__global__ __launch_bounds__(1024) void k_fine(const int* __restrict__ cursor,
                                               const uint32_t* __restrict__ buck,
                                               int* __restrict__ offsets,
                                               uint32_t* __restrict__ fsr,
                                               int N, int E) {
  __shared__ int hist[256];
  __shared__ int cur[256];
  __shared__ int wsum8[8];
  __shared__ int wsum[4];
  __shared__ int b0_sh;
  __shared__ uint32_t stage[FINE_CAP];
  int b = blockIdx.x;
  int t = threadIdx.x;
  int lane = t & 63;
  int cnt = cursor[b] - b * CAP;
  const uint32_t* bk = buck + (size_t)b * CAP;
  int node = (b << 8) + (t & 255);

  // local 512-wide exclusive scan of bucket counts -> b0 (element b)
  int sv = 0, sincl = 0, sw8 = t >> 6;
  if (t < 512) {
    sv = cursor[t] - t * CAP;
    sincl = sv;
#pragma unroll
    for (int d = 1; d < 64; d <<= 1) {
      int o = __shfl_up(sincl, d);
      if (lane >= d) sincl += o;
    }
    if (lane == 63) wsum8[sw8] = sincl;
  }
  if (t < 256) hist[t] = 0;
  __syncthreads();
  if (t < 512) {
    int woff = 0;
    for (int i = 0; i < sw8; ++i) woff += wsum8[i];
    int excl = woff + sincl - sv;
    if (t == b) b0_sh = excl;
  }
  __syncthreads();
  int b0 = b0_sh;

  for (int i = t; i < cnt; i += 1024) atomicAdd(&hist[bk[i] >> 17], 1);
  __syncthreads();
  int v = 0, incl = 0;
  int w4 = t >> 6;
  if (t < 256) {
    v = hist[t];
    incl = v;
#pragma unroll
    for (int d = 1; d < 64; d <<= 1) {
      int o = __shfl_up(incl, d);
      if (lane >= d) incl += o;
    }
    if (lane == 63) wsum[w4] = incl;
  }
  __syncthreads();
  if (t < 256) {
    int woff = 0;
    for (int i = 0; i < w4; ++i) woff += wsum[i];
    int excl = woff + incl - v;
    cur[t] = excl;
    if (node < N) offsets[node] = b0 + excl;
  }
  if (b == 0 && t == 0) offsets[N] = E;
  __syncthreads();
  for (int i = t; i < cnt; i += 1024) {
    uint32_t r = bk[i];
    int pos = atomicAdd(&cur[r >> 17], 1);
    stage[pos] = r;
  }
  __syncthreads();
  for (int i = t; i < cnt; i += 1024) fsr[b0 + i] = stage[i];
}

// Proven R3/R5/R6 gather pipeline (shfl meta, depth 5, 44 VGPR).
// Model (R0-R8): k_agg is bound by the per-CU line-fill miss path (~108-112us
// floor). Do not add line-missing VMEM; do not cross the 64-VGPR cliff; do
// not clamp min-waves (R2 spill disaster).
#define AGG_LOAD(K, JJ)                                                   \
  {                                                                       \
    int e_ = ((JJ) * 4 + g) & 63;                                         \
    int ss_ = __shfl(s_l, e_);                                            \
    float ww_ = __shfl(w_l, e_);                                          \
    w##K = ((JJ) < iters) ? ww_ : 0.f;                                    \
    u##K = *(const uint4*)&hb[(size_t)ss_ * 128 + l16 * 8];               \
  }

#define AGG_FMA(K)                                                        \
  {                                                                       \
    acc[0] += w##K * __uint_as_float(u##K.x << 16);                       \
    acc[1] += w##K * __uint_as_float(u##K.x & 0xffff0000u);               \
    acc[2] += w##K * __uint_as_float(u##K.y << 16);                       \
    acc[3] += w##K * __uint_as_float(u##K.y & 0xffff0000u);               \
    acc[4] += w##K * __uint_as_float(u##K.z << 16);                       \
    acc[5] += w##K * __uint_as_float(u##K.z & 0xffff0000u);               \
    acc[6] += w##K * __uint_as_float(u##K.w << 16);                       \
    acc[7] += w##K * __uint_as_float(u##K.w & 0xffff0000u);               \
  }

__global__ __launch_bounds__(256) void k_agg(const int* __restrict__ offs,
                                             const uint32_t* __restrict__ fsr,
                                             const float* __restrict__ a_s,
                                             const float* __restrict__ a_d,
                                             const unsigned short* __restrict__ hb,
                                             const float* __restrict__ bias,
                                             float* __restrict__ out, int N) {
  int lane = threadIdx.x & 63;
  int n = blockIdx.x * 4 + (threadIdx.x >> 6);
  if (n >= N) return;
  int g = lane >> 4;        // edge group 0..3
  int l16 = lane & 15;      // 16B slot within the 256B row
  float acc[8] = {};
  float sum = 0.f;
  int s0 = offs[n], s1 = offs[n + 1];
  float adn = a_d[n];

  for (int base = s0; base < s1; base += 64) {
    int idx = base + lane;
    int s_l = 0;
    float w_l = 0.f;
    if (idx < s1) {
      uint32_t r = fsr[idx];
      s_l = (int)(r & 0x1ffffu);
      float e = a_s[s_l] + adn;
      e = (e > 0.f) ? e : NEG * e;
      w_l = __expf(e);
    }
    sum += w_l;
    int cnt = min(64, s1 - base);
    int iters = (cnt + 3) >> 2;
    uint4 u0, u1, u2, u3, u4;
    float w0, w1, w2, w3, w4;
    AGG_LOAD(0, 0) AGG_LOAD(1, 1) AGG_LOAD(2, 2)
    AGG_LOAD(3, 3) AGG_LOAD(4, 4)
    int j = 0;
    for (; j + 5 < iters; j += 5) {
      AGG_FMA(0) AGG_LOAD(0, j + 5)
      AGG_FMA(1) AGG_LOAD(1, j + 6)
      AGG_FMA(2) AGG_LOAD(2, j + 7)
      AGG_FMA(3) AGG_LOAD(3, j + 8)
      AGG_FMA(4) AGG_LOAD(4, j + 9)
    }
    AGG_FMA(0) AGG_FMA(1) AGG_FMA(2) AGG_FMA(3) AGG_FMA(4)
  }
#pragma unroll
  for (int d = 1; d <= 32; d <<= 1) sum += __shfl_xor(sum, d);
#pragma unroll
  for (int d = 16; d <= 32; d <<= 1) {
#pragma unroll
    for (int i = 0; i < 8; ++i) acc[i] += __shfl_xor(acc[i], d);
  }
  float inv = 1.0f / (sum + 1e-16f);
  if (lane < 32) {
    int half = g & 1;                     // 0 for lanes 0-15, 1 for 16-31
    int f = l16 * 8 + half * 4;
    float4 bv = *(const float4*)&bias[f];
    float4 o;
    o.x = fmaxf(acc[half * 4 + 0] * inv + bv.x, 0.f);
    o.y = fmaxf(acc[half * 4 + 1] * inv + bv.y, 0.f);
    o.z = fmaxf(acc[half * 4 + 2] * inv + bv.z, 0.f);
    o.w = fmaxf(acc[half * 4 + 3] * inv + bv.w, 0.f);
    *(float4*)&out[(size_t)n * 128 + f] = o;
  }
}

// ---------------------------------------------------------------------------
// MERGED PATH (R9): k_fine fused into the aggregator. One block per coarse
// bucket (1024 threads, 16 waves, ~45KB LDS -> 2 blocks/CU = 32 waves/CU).
// Phase 1 = k_fine's counting sort into LDS stage[] (no fsr/offsets
// round-trip: deletes 25.6MB of traffic + one launch). Phase 2 = each wave
// runs the PROVEN gather pipeline for 16 nodes; meta comes from LDS.
// The sort work hides inside the miss-queue-saturated gather phase of
// other resident waves. Requires buck in ws (no d_out aliasing with out
// writes) -> only taken when ws_size suffices; else fallback above.
// ---------------------------------------------------------------------------
__global__ __launch_bounds__(1024) void k_aggf(const int* __restrict__ cursor,
                                               const uint32_t* __restrict__ buck,
                                               const float* __restrict__ a_s,
                                               const float* __restrict__ a_d,
                                               const unsigned short* __restrict__ hb,
                                               const float* __restrict__ bias,
                                               float* __restrict__ out, int N) {
  __shared__ int hist[256];
  __shared__ int cur[256];
  __shared__ int excl_k[256];
  __shared__ int wsum[4];
  __shared__ uint32_t stage[FINE_CAP];
  int b = blockIdx.x;
  int t = threadIdx.x;
  int lane = t & 63;
  int cnt = cursor[b] - b * CAP;
  const uint32_t* bk = buck + (size_t)b * CAP;

  if (t < 256) hist[t] = 0;
  __syncthreads();
  for (int i = t; i < cnt; i += 1024) atomicAdd(&hist[bk[i] >> 17], 1);
  __syncthreads();
  int v = 0, incl = 0;
  int w4 = t >> 6;
  if (t < 256) {
    v = hist[t];
    incl = v;
#pragma unroll
    for (int d = 1; d < 64; d <<= 1) {
      int o = __shfl_up(incl, d);
      if (lane >= d) incl += o;
    }
    if (lane == 63) wsum[w4] = incl;
  }
  __syncthreads();
  if (t < 256) {
    int woff = 0;
    for (int i = 0; i < w4; ++i) woff += wsum[i];
    int excl = woff + incl - v;
    cur[t] = excl;
    excl_k[t] = excl;
  }
  __syncthreads();
  for (int i = t; i < cnt; i += 1024) {
    uint32_t r = bk[i];
    int pos = atomicAdd(&cur[r >> 17], 1);
    stage[pos] = r;
  }
  __syncthreads();

  // ---- aggregate: wave wv handles local nodes wv*16 .. wv*16+15 ----
  int wv = t >> 6;          // 0..15 (wave-uniform)
  int g = lane >> 4;
  int l16 = lane & 15;
  for (int i = 0; i < 16; ++i) {
    int ln = wv * 16 + i;
    int n = (b << 8) + ln;
    if (n >= N) break;                    // wave-uniform
    int e0 = excl_k[ln];
    int e1 = e0 + hist[ln];               // hist intact (sort bumped cur only)
    float adn = a_d[n];
    float acc[8] = {};
    float sum = 0.f;
    for (int base = e0; base < e1; base += 64) {
      int idx = base + lane;
      int s_l = 0;
      float w_l = 0.f;
      if (idx < e1) {
        uint32_t r = stage[idx];
        s_l = (int)(r & 0x1ffffu);
        float e = a_s[s_l] + adn;
        e = (e > 0.f) ? e : NEG * e;
        w_l = __expf(e);
      }
      sum += w_l;
      int cnt2 = min(64, e1 - base);
      int iters = (cnt2 + 3) >> 2;
      uint4 u0, u1, u2, u3, u4;
      float w0, w1, w2, w3, w4;
      AGG_LOAD(0, 0) AGG_LOAD(1, 1) AGG_LOAD(2, 2)
      AGG_LOAD(3, 3) AGG_LOAD(4, 4)
      int j = 0;
      for (; j + 5 < iters; j += 5) {
        AGG_FMA(0) AGG_LOAD(0, j + 5)
        AGG_FMA(1) AGG_LOAD(1, j + 6)
        AGG_FMA(2) AGG_LOAD(2, j + 7)
        AGG_FMA(3) AGG_LOAD(3, j + 8)
        AGG_FMA(4) AGG_LOAD(4, j + 9)
      }
      AGG_FMA(0) AGG_FMA(1) AGG_FMA(2) AGG_FMA(3) AGG_FMA(4)
    }
#pragma unroll
    for (int d = 1; d <= 32; d <<= 1) sum += __shfl_xor(sum, d);
#pragma unroll
    for (int d = 16; d <= 32; d <<= 1) {
#pragma unroll
      for (int k = 0; k < 8; ++k) acc[k] += __shfl_xor(acc[k], d);
    }
    float inv = 1.0f / (sum + 1e-16f);
    if (lane < 32) {
      int half = g & 1;
      int f = l16 * 8 + half * 4;
      float4 bv = *(const float4*)&bias[f];
      float4 o;
      o.x = fmaxf(acc[half * 4 + 0] * inv + bv.x, 0.f);
      o.y = fmaxf(acc[half * 4 + 1] * inv + bv.y, 0.f);
      o.z = fmaxf(acc[half * 4 + 2] * inv + bv.z, 0.f);
      o.w = fmaxf(acc[half * 4 + 3] * inv + bv.w, 0.f);
      *(float4*)&out[(size_t)n * 128 + f] = o;
    }
  }
}

// ---------------------------------------------------------------------------
extern "C" void kernel_launch(void* const* d_in, const int* in_sizes, int n_in,
                              void* d_out, int out_size, void* d_ws, size_t ws_size,
                              hipStream_t stream) {
  const float* x = (const float*)d_in[0];
  const void* ei = d_in[1];
  const float* W = (const float*)d_in[2];
  const float* att_s = (const float*)d_in[3];
  const float* att_d = (const float*)d_in[4];
  const float* bias = (const float*)d_in[5];
  float* out = (float*)d_out;

  const int N = in_sizes[0] / 128;
  const int E = in_sizes[1] / 2;
  const int NB = (N + 255) >> 8;      // coarse buckets (<=512 for N<=131072)

  uint8_t* ws = (uint8_t*)d_ws;
  size_t off = 0;
  auto alloc = [&](size_t bytes) -> void* {
    void* p = ws + off;
    off = (off + bytes + 511) & ~(size_t)511;
    return p;
  };
  // common allocations (~26.5MB)
  int* flag = (int*)alloc(4);
  int* bcur = (int*)alloc(512 * 4);
  unsigned short* Wt = (unsigned short*)alloc(128 * 128 * 2);
  unsigned short* hb = (unsigned short*)alloc((size_t)N * 128 * 2);
  float* a_s = (float*)alloc((size_t)N * 4);
  float* a_d = (float*)alloc((size_t)N * 4);
  (void)n_in; (void)out_size;

  const size_t buck_bytes = (size_t)NB * CAP * 4;     // 16.8MB @ N=100K
  const bool merged = (ws_size >= off + buck_bytes + 4096);

  const int ngemm = (N + 63) / 64;
  const int nms = (E + MS_CHUNK - 1) / MS_CHUNK;
  int grid = ngemm + nms;
  if (grid < 3 * nms - 2) grid = 3 * nms - 2;   // ms coverage: 3*(nms-1) < grid

  if (merged) {
    // buck in ws: no aliasing between bucket reads and out writes.
    uint32_t* buck = (uint32_t*)alloc(buck_bytes);
    k_detect<<<8, 512, 0, stream>>>((const int*)ei, flag, bcur, W, Wt);
    k_fused<<<grid, 256, 0, stream>>>(x, Wt, att_s, att_d, hb, a_s, a_d, N,
                                      ei, flag, bcur, buck, E, nms);
    k_aggf<<<NB, 1024, 0, stream>>>(bcur, buck, a_s, a_d, hb, bias, out, N);
  } else {
    // proven R8 fallback: buck scratch in d_out (dead until k_agg, which
    // fully rewrites out afterwards; deterministic across replays).
    int* offsets = (int*)alloc((size_t)(N + 1) * 4);
    uint32_t* fsr = (uint32_t*)alloc((size_t)E * 4);
    uint32_t* buck = (uint32_t*)d_out;   // NB*CAP*4 <= 17MB <= out 51.2MB
    k_detect<<<8, 512, 0, stream>>>((const int*)ei, flag, bcur, W, Wt);
    k_fused<<<grid, 256, 0, stream>>>(x, Wt, att_s, att_d, hb, a_s, a_d, N,
                                      ei, flag, bcur, buck, E, nms);
    k_fine<<<NB, 1024, 0, stream>>>(bcur, buck, offsets, fsr, N, E);
    k_agg<<<(N + 3) / 4, 256, 0, stream>>>(offsets, fsr, a_s, a_d, hb, bias, out, N);
  }
}

// Round 10
// 185.045 us; speedup vs baseline: 1.0959x; 1.0959x over previous
//
#include <hip/hip_runtime.h>
#include <cstdint>
#include <cstddef>

#define NEG 0.2f
#define CAP 10752          // padded per-bucket capacity (mean 8192, +28 sigma)
#define FINE_CAP CAP

typedef __attribute__((ext_vector_type(8))) short short8;   // 8 bf16 (4 VGPR)
typedef __attribute__((ext_vector_type(4))) float f32x4;    // MFMA acc

// ---------------------------------------------------------------------------
// bf16 helpers (RNE)
// ---------------------------------------------------------------------------
__device__ __forceinline__ unsigned short f2bf(float f) {
  unsigned u = __float_as_uint(f);
  unsigned r = (u + 0x7fffu + ((u >> 16) & 1u)) >> 16;
  return (unsigned short)r;
}

// ---------------------------------------------------------------------------
// Edge dtype sniff + cursor init + W transpose to bf16 Wt[col][k].
// R8: 8 blocks (was 1). The single-block version was a serial ~64KB-read
// latency hit at the head of the pipeline. Each thread handles exactly one
// float4 of W; block 0 additionally does flag + cursor init.
// ---------------------------------------------------------------------------
__global__ __launch_bounds__(512) void k_detect(const int* __restrict__ ei32,
                                                int* __restrict__ flag,
                                                int* __restrict__ cursor,
                                                const float* __restrict__ W,
                                                unsigned short* __restrict__ Wt) {
  int t = threadIdx.x;                 // 512 threads
  int b = blockIdx.x;                  // 8 blocks
  if (b == 0) {
    cursor[t] = t * CAP;
    if (t < 64) {
      int v = ei32[2 * t + 1];
      unsigned long long bl = __ballot(v != 0);
      if (t == 0) flag[0] = (bl == 0ULL) ? 1 : 0;   // 1 = int64, 0 = int32
    }
  }
  // transpose 128x128 W (f32, row-major [k][c]) -> Wt bf16 [c][k]
  int idx = b * 512 + t;               // float4 index, 4096 total
  float4 v = ((const float4*)W)[idx];
  int k = idx >> 5;                    // 32 float4 per row
  int c = (idx & 31) * 4;
  Wt[(c + 0) * 128 + k] = f2bf(v.x);
  Wt[(c + 1) * 128 + k] = f2bf(v.y);
  Wt[(c + 2) * 128 + k] = f2bf(v.z);
  Wt[(c + 3) * 128 + k] = f2bf(v.w);
}

__device__ __forceinline__ int edge_val(const void* ei, long long idx, int is64) {
  return is64 ? (int)((const long long*)ei)[idx] : ((const int*)ei)[idx];
}

// ---------------------------------------------------------------------------
// FUSED gemm (MFMA, no LDS) + msplit (4KB LDS) kernel, 256 threads both roles.
// Ms blocks at gid%3==0; coverage grid = max(ngemm+nms, 3*nms-2); gemm_id
// bijective and sequential. [R7 lesson: do NOT add large __shared__ here —
// it is allocated by GEMM-role blocks too and tanks their occupancy. R9
// lesson: do NOT fuse the sort into the aggregator either — 2 blocks/CU
// occupancy cap + serial sort phase cost +19us. The simple 4-kernel
// pipeline is the proven optimum.]
//
// gemm role (4 waves x 16 rows): h = x @ W via mfma_f32_16x16x32_bf16.
// Epilogue: bf16 h + a_s/a_d dots.
//
// ms role: scatter packed records (dst&255)<<17|src into padded coarse
// buckets (bucket = dst>>8), 4096 edges/block, LDS hist for ranks, one
// global atomic per nonzero bin.
// ---------------------------------------------------------------------------
#define MS_CHUNK 4096
__global__ __launch_bounds__(256) void k_fused(
    const float* __restrict__ x, const unsigned short* __restrict__ Wt,
    const float* __restrict__ as_, const float* __restrict__ ad_,
    unsigned short* __restrict__ hb, float* __restrict__ a_s,
    float* __restrict__ a_d, int N,
    const void* __restrict__ ei, const int* __restrict__ flag,
    int* __restrict__ cursor, uint32_t* __restrict__ buck, int E, int nms) {
  __shared__ int hist[512];
  __shared__ int resv[512];
  int gid = blockIdx.x;
  int t = threadIdx.x;
  bool is_ms = ((gid % 3) == 0) && ((gid / 3) < nms);

  if (is_ms) {
    // ---------------- msplit ----------------
    int bid = gid / 3;
    const int is64 = flag[0];
    for (int i = t; i < 512; i += 256) hist[i] = 0;
    __syncthreads();
    long long base = (long long)bid * MS_CHUNK;
    uint32_t rec[16];
    int bb[16], rk[16];
#pragma unroll
    for (int i = 0; i < 16; ++i) {
      long long idx = base + i * 256 + t;
      bb[i] = -1;
      if (idx < E) {
        int s = edge_val(ei, idx, is64);
        int d = edge_val(ei, (long long)E + idx, is64);
        bb[i] = d >> 8;
        rec[i] = ((uint32_t)(d & 255) << 17) | (uint32_t)s;
        rk[i] = atomicAdd(&hist[bb[i]], 1);
      }
    }
    __syncthreads();
    for (int b = t; b < 512; b += 256) {
      int c = hist[b];
      resv[b] = c ? atomicAdd(&cursor[b], c) : 0;
    }
    __syncthreads();
#pragma unroll
    for (int i = 0; i < 16; ++i) {
      if (bb[i] >= 0) buck[(size_t)resv[bb[i]] + rk[i]] = rec[i];
    }
    return;
  }

  // ---------------- gemm (MFMA) ----------------
  int gemm_id = gid - min(gid / 3 + 1, nms);
  int lane = t & 63;
  int wv = t >> 6;                         // 4 waves
  int row0 = gemm_id * 64 + wv * 16;
  int r = lane & 15, o = lane >> 4;

  int arow = row0 + r;
  if (arow >= N) arow = N - 1;
  const float* xr = x + (size_t)arow * 128 + o * 8;
  short8 a[4];
#pragma unroll
  for (int kt = 0; kt < 4; ++kt) {
    float4 lo = *(const float4*)(xr + kt * 32);
    float4 hi = *(const float4*)(xr + kt * 32 + 4);
    short8 av;
    av[0] = (short)f2bf(lo.x); av[1] = (short)f2bf(lo.y);
    av[2] = (short)f2bf(lo.z); av[3] = (short)f2bf(lo.w);
    av[4] = (short)f2bf(hi.x); av[5] = (short)f2bf(hi.y);
    av[6] = (short)f2bf(hi.z); av[7] = (short)f2bf(hi.w);
    a[kt] = av;
  }

  float ats[8], atd[8];
#pragma unroll
  for (int ct = 0; ct < 8; ++ct) {
    ats[ct] = as_[ct * 16 + r];
    atd[ct] = ad_[ct * 16 + r];
  }

  f32x4 acc[8];
#pragma unroll
  for (int ct = 0; ct < 8; ++ct) acc[ct] = (f32x4){0.f, 0.f, 0.f, 0.f};
#pragma unroll
  for (int ct = 0; ct < 8; ++ct) {
    const unsigned short* wb = Wt + ((size_t)(ct * 16 + r)) * 128 + o * 8;
#pragma unroll
    for (int kt = 0; kt < 4; ++kt) {
      short8 b = *(const short8*)(wb + kt * 32);
      acc[ct] = __builtin_amdgcn_mfma_f32_16x16x32_bf16(a[kt], b, acc[ct], 0, 0, 0);
    }
  }

#pragma unroll
  for (int j = 0; j < 4; ++j) {
    int row = row0 + o * 4 + j;
    bool ok = row < N;
    float ps = 0.f, pd = 0.f;
#pragma unroll
    for (int ct = 0; ct < 8; ++ct) {
      float v = acc[ct][j];
      if (ok) hb[(size_t)row * 128 + ct * 16 + r] = f2bf(v);
      ps += v * ats[ct];
      pd += v * atd[ct];
    }
#pragma unroll
    for (int d = 1; d <= 8; d <<= 1) {
      ps += __shfl_xor(ps, d);
      pd += __shfl_xor(pd, d);
    }
    if (ok && r == 0) { a_s[row] = ps; a_d[row] = pd; }
  }
}

// ---------------------------------------------------------------------------
// Fine sort within each bucket -> offsets + fine-sorted RAW 4B records.
// R6: no exp / no sw int2 output; softmax weight recomputed in k_agg.
// 1024 threads/block; k_bscan merged (local 512-scan).
// ---------------------------------------------------------------------------
__global__ __launch_bounds__(1024) void k_fine(const int* __restrict__ cursor,
                                               const uint32_t* __restrict__ buck,
                                               int* __restrict__ offsets,
                                               uint32_t* __restrict__ fsr,
                                               int N, int E) {
  __shared__ int hist[256];
  __shared__ int cur[256];
  __shared__ int wsum8[8];
  __shared__ int wsum[4];
  __shared__ int b0_sh;
  __shared__ uint32_t stage[FINE_CAP];
  int b = blockIdx.x;
  int t = threadIdx.x;
  int lane = t & 63;
  int cnt = cursor[b] - b * CAP;
  const uint32_t* bk = buck + (size_t)b * CAP;
  int node = (b << 8) + (t & 255);

  // local 512-wide exclusive scan of bucket counts -> b0 (element b)
  int sv = 0, sincl = 0, sw8 = t >> 6;
  if (t < 512) {
    sv = cursor[t] - t * CAP;
    sincl = sv;
#pragma unroll
    for (int d = 1; d < 64; d <<= 1) {
      int o = __shfl_up(sincl, d);
      if (lane >= d) sincl += o;
    }
    if (lane == 63) wsum8[sw8] = sincl;
  }
  if (t < 256) hist[t] = 0;
  __syncthreads();
  if (t < 512) {
    int woff = 0;
    for (int i = 0; i < sw8; ++i) woff += wsum8[i];
    int excl = woff + sincl - sv;
    if (t == b) b0_sh = excl;
  }
  __syncthreads();
  int b0 = b0_sh;

  for (int i = t; i < cnt; i += 1024) atomicAdd(&hist[bk[i] >> 17], 1);
  __syncthreads();
  int v = 0, incl = 0;
  int w4 = t >> 6;
  if (t < 256) {
    v = hist[t];
    incl = v;
#pragma unroll
    for (int d = 1; d < 64; d <<= 1) {
      int o = __shfl_up(incl, d);
      if (lane >= d) incl += o;
    }
    if (lane == 63) wsum[w4] = incl;
  }
  __syncthreads();
  if (t < 256) {
    int woff = 0;
    for (int i = 0; i < w4; ++i) woff += wsum[i];
    int excl = woff + incl - v;
    cur[t] = excl;
    if (node < N) offsets[node] = b0 + excl;
  }
  if (b == 0 && t == 0) offsets[N] = E;
  __syncthreads();
  for (int i = t; i < cnt; i += 1024) {
    uint32_t r = bk[i];
    int pos = atomicAdd(&cur[r >> 17], 1);
    stage[pos] = r;
  }
  __syncthreads();
  for (int i = t; i < cnt; i += 1024) fsr[b0 + i] = stage[i];
}

// ---------------------------------------------------------------------------
// Per-node weighted feature gather — proven R3/R5 core loop (shfl meta,
// depth 5, 44 VGPR). R6: meta phase reads the 4B raw record and recomputes
// w = exp(leaky(a_s[src] + a_d[n])) on the fly (a_s 400KB L2-resident).
// Model (R0-R9): k_agg is bound by the per-CU vector-memory line-fill path
// (~108-112us floor: E*2 128B line fills at ~0.1 line/cy/CU). Probes:
// depth 4/5 identical; half waves -22%; +VMEM instrs regress; fusion with
// the sort (R9) regresses via occupancy loss. Do not add line-missing
// VMEM; do not cross the 64-VGPR cliff; do not clamp min-waves (R2:
// forced 32 VGPR -> 1.19GB scratch spill).
// ---------------------------------------------------------------------------
#define AGG_LOAD(K, JJ)                                                   \
  {                                                                       \
    int e_ = ((JJ) * 4 + g) & 63;                                         \
    int ss_ = __shfl(s_l, e_);                                            \
    float ww_ = __shfl(w_l, e_);                                          \
    w##K = ((JJ) < iters) ? ww_ : 0.f;                                    \
    u##K = *(const uint4*)&hb[(size_t)ss_ * 128 + l16 * 8];               \
  }

#define AGG_FMA(K)                                                        \
  {                                                                       \
    acc[0] += w##K * __uint_as_float(u##K.x << 16);                       \
    acc[1] += w##K * __uint_as_float(u##K.x & 0xffff0000u);               \
    acc[2] += w##K * __uint_as_float(u##K.y << 16);                       \
    acc[3] += w##K * __uint_as_float(u##K.y & 0xffff0000u);               \
    acc[4] += w##K * __uint_as_float(u##K.z << 16);                       \
    acc[5] += w##K * __uint_as_float(u##K.z & 0xffff0000u);               \
    acc[6] += w##K * __uint_as_float(u##K.w << 16);                       \
    acc[7] += w##K * __uint_as_float(u##K.w & 0xffff0000u);               \
  }

__global__ __launch_bounds__(256) void k_agg(const int* __restrict__ offs,
                                             const uint32_t* __restrict__ fsr,
                                             const float* __restrict__ a_s,
                                             const float* __restrict__ a_d,
                                             const unsigned short* __restrict__ hb,
                                             const float* __restrict__ bias,
                                             float* __restrict__ out, int N) {
  int lane = threadIdx.x & 63;
  int n = blockIdx.x * 4 + (threadIdx.x >> 6);
  if (n >= N) return;
  int g = lane >> 4;        // edge group 0..3
  int l16 = lane & 15;      // 16B slot within the 256B row
  float acc[8] = {};
  float sum = 0.f;
  int s0 = offs[n], s1 = offs[n + 1];
  float adn = a_d[n];

  for (int base = s0; base < s1; base += 64) {
    int idx = base + lane;
    int s_l = 0;
    float w_l = 0.f;
    if (idx < s1) {
      uint32_t r = fsr[idx];
      s_l = (int)(r & 0x1ffffu);
      float e = a_s[s_l] + adn;
      e = (e > 0.f) ? e : NEG * e;
      w_l = __expf(e);
    }
    sum += w_l;
    int cnt = min(64, s1 - base);
    int iters = (cnt + 3) >> 2;
    uint4 u0, u1, u2, u3, u4;
    float w0, w1, w2, w3, w4;
    AGG_LOAD(0, 0) AGG_LOAD(1, 1) AGG_LOAD(2, 2)
    AGG_LOAD(3, 3) AGG_LOAD(4, 4)
    int j = 0;
    for (; j + 5 < iters; j += 5) {
      AGG_FMA(0) AGG_LOAD(0, j + 5)
      AGG_FMA(1) AGG_LOAD(1, j + 6)
      AGG_FMA(2) AGG_LOAD(2, j + 7)
      AGG_FMA(3) AGG_LOAD(3, j + 8)
      AGG_FMA(4) AGG_LOAD(4, j + 9)
    }
    AGG_FMA(0) AGG_FMA(1) AGG_FMA(2) AGG_FMA(3) AGG_FMA(4)
  }
#pragma unroll
  for (int d = 1; d <= 32; d <<= 1) sum += __shfl_xor(sum, d);
#pragma unroll
  for (int d = 16; d <= 32; d <<= 1) {
#pragma unroll
    for (int i = 0; i < 8; ++i) acc[i] += __shfl_xor(acc[i], d);
  }
  float inv = 1.0f / (sum + 1e-16f);
  if (lane < 32) {
    int half = g & 1;                     // 0 for lanes 0-15, 1 for 16-31
    int f = l16 * 8 + half * 4;
    float4 bv = *(const float4*)&bias[f];
    float4 o;
    o.x = fmaxf(acc[half * 4 + 0] * inv + bv.x, 0.f);
    o.y = fmaxf(acc[half * 4 + 1] * inv + bv.y, 0.f);
    o.z = fmaxf(acc[half * 4 + 2] * inv + bv.z, 0.f);
    o.w = fmaxf(acc[half * 4 + 3] * inv + bv.w, 0.f);
    *(float4*)&out[(size_t)n * 128 + f] = o;
  }
}

// ---------------------------------------------------------------------------
extern "C" void kernel_launch(void* const* d_in, const int* in_sizes, int n_in,
                              void* d_out, int out_size, void* d_ws, size_t ws_size,
                              hipStream_t stream) {
  const float* x = (const float*)d_in[0];
  const void* ei = d_in[1];
  const float* W = (const float*)d_in[2];
  const float* att_s = (const float*)d_in[3];
  const float* att_d = (const float*)d_in[4];
  const float* bias = (const float*)d_in[5];
  float* out = (float*)d_out;

  const int N = in_sizes[0] / 128;
  const int E = in_sizes[1] / 2;
  const int NB = (N + 255) >> 8;      // coarse buckets (<=512 for N<=131072)

  uint8_t* ws = (uint8_t*)d_ws;
  size_t off = 0;
  auto alloc = [&](size_t bytes) -> void* {
    void* p = ws + off;
    off = (off + bytes + 511) & ~(size_t)511;
    return p;
  };
  int* flag = (int*)alloc(4);
  int* bcur = (int*)alloc(512 * 4);
  unsigned short* Wt = (unsigned short*)alloc(128 * 128 * 2);
  int* offsets = (int*)alloc((size_t)(N + 1) * 4);
  uint32_t* fsr = (uint32_t*)alloc((size_t)E * 4);
  unsigned short* hb = (unsigned short*)alloc((size_t)N * 128 * 2);
  float* a_s = (float*)alloc((size_t)N * 4);
  float* a_d = (float*)alloc((size_t)N * 4);
  // Padded bucket scratch lives in d_out: dead until k_agg, which fully
  // rewrites out for every node afterwards (deterministic across replays).
  uint32_t* buck = (uint32_t*)d_out;   // NB*CAP*4 <= 17MB <= out 51.2MB
  (void)ws_size; (void)n_in; (void)out_size;

  const int ngemm = (N + 63) / 64;
  const int nms = (E + MS_CHUNK - 1) / MS_CHUNK;
  int grid = ngemm + nms;
  if (grid < 3 * nms - 2) grid = 3 * nms - 2;   // ms coverage: 3*(nms-1) < grid

  k_detect<<<8, 512, 0, stream>>>((const int*)ei, flag, bcur, W, Wt);
  k_fused<<<grid, 256, 0, stream>>>(x, Wt, att_s, att_d, hb, a_s, a_d, N,
                                    ei, flag, bcur, buck, E, nms);
  k_fine<<<NB, 1024, 0, stream>>>(bcur, buck, offsets, fsr, N, E);
  k_agg<<<(N + 3) / 4, 256, 0, stream>>>(offsets, fsr, a_s, a_d, hb, bias, out, N);
}